// Round 8
// baseline (2462.830 us; speedup 1.0000x reference)
//
#include <hip/hip_runtime.h>
#include <hip/hip_cooperative_groups.h>

#define NB 16
#define NS 12
#define NN 2048
#define NE 32768
#define NROWS (NB*NN)          // 32768 rows of 64
#define DTC  0.1f
#define DT2C 0.05f
#define DT6C (0.1f/6.0f)
#define LOG2E 1.44269504088896f
#define CSRCAP 49152           // NE + pad(<=7*NN) rounded up

// Node-major state: row tn = n*16 + b.
// ht packed: uint2 at [(n*4+bg)*64 + c] = bf16 h for batches bg*4..bg*4+3, column c.
// est/edt: [n*64 + b*4 + head], pre-scaled by LOG2E.  est has a SENTINEL row at
// n=NN filled with -1e30 (exp2 -> 0) so CSR is padded to multiples of 8 edges.
// ht/est/edt double-buffered across evals. y/acc live in registers in the
// persistent cooperative kernel. 256 blocks x 1024 thr = 1 block/CU (robustly
// co-residable: 16 waves/CU, 49.6KB LDS < 64KB, VGPR<=128 via bounds(1024,4)).
// Each block owns 8 nodes (128 rows), processed as two 64-row passes per eval.

__device__ __forceinline__ unsigned short f2bf(float f) {
    unsigned int u = __float_as_uint(f);
    u = u + 0x7fffu + ((u >> 16) & 1u);      // RTNE
    return (unsigned short)(u >> 16);
}
__device__ __forceinline__ float fexp2(float x) {
#if __has_builtin(__builtin_amdgcn_exp2f)
    return __builtin_amdgcn_exp2f(x);
#else
    return __expf(x * 0.69314718056f);
#endif
}

// ---------------- prep: zero deg, sentinel-fill csr, sentinel est rows ----------------
__global__ __launch_bounds__(256) void prep_k(int* __restrict__ deg, int* __restrict__ csr,
    float* __restrict__ estA, float* __restrict__ estB)
{
    int t = blockIdx.x * 256 + threadIdx.x;
    if (t < NN) deg[t] = 0;
    if (t < CSRCAP) csr[t] = NN;               // sentinel node
    if (t < 64) {
        estA[(size_t)NN * 64 + t] = -1e30f;    // exp2 -> 0
        estB[(size_t)NN * 64 + t] = -1e30f;
    }
}
__global__ __launch_bounds__(256) void count_deg_k(const int* __restrict__ dst, int* __restrict__ deg)
{
    int e = blockIdx.x * 256 + threadIdx.x;
    if (e < NE) atomicAdd(&deg[dst[e]], 1);
}
// prefix-sum of PADDED degrees (pad to multiple of 8)
__global__ __launch_bounds__(1024) void scan_k(const int* __restrict__ deg,
    int* __restrict__ offs, int* __restrict__ cursor)
{
    __shared__ int p[1024];
    int t = threadIdx.x;
    int d0 = (deg[2 * t] + 7) & ~7;
    int d1 = (deg[2 * t + 1] + 7) & ~7;
    p[t] = d0 + d1;
    __syncthreads();
    for (int d = 1; d < 1024; d <<= 1) {
        int v = (t >= d) ? p[t - d] : 0;
        __syncthreads();
        p[t] += v;
        __syncthreads();
    }
    int excl = (t > 0) ? p[t - 1] : 0;     // exclusive pair-sum
    offs[2 * t] = excl;       offs[2 * t + 1] = excl + d0;
    cursor[2 * t] = excl;     cursor[2 * t + 1] = excl + d0;
    if (t == 1023) offs[2048] = p[1023];
}
__global__ __launch_bounds__(256) void scatter_k(const int* __restrict__ src, const int* __restrict__ dst,
    int* __restrict__ cursor, int* __restrict__ csr)
{
    int e = blockIdx.x * 256 + threadIdx.x;
    if (e < NE) {
        int pos = atomicAdd(&cursor[dst[e]], 1);
        csr[pos] = src[e];
    }
}

// ---------------- PERSISTENT: all 12 RK4 steps (49 evals) in one launch ----------------
__global__ __launch_bounds__(1024, 4) void persist_k(
    const float* __restrict__ inputs, const float* __restrict__ w_in, const float* __restrict__ b_in,
    uint2* __restrict__ htA, float* __restrict__ estA, float* __restrict__ edtA,
    uint2* __restrict__ htB, float* __restrict__ estB, float* __restrict__ edtB,
    const int* __restrict__ offs, const int* __restrict__ csr, const float* __restrict__ bias_g,
    const float* __restrict__ Wh, const float* __restrict__ a_src, const float* __restrict__ a_dst,
    float* __restrict__ yout)
{
    __shared__ float kvs[64 * 64];             // k for current 64-row pass
    __shared__ float Zs[64 * 65];              // Zs[k][r], pad 65
    __shared__ unsigned int Hs[64 * 33];       // bf16-pair matrix [row][colpair], pad 33
    __shared__ float Ps[16][64];
    __shared__ float Pd[16][64];

    cooperative_groups::grid_group grid = cooperative_groups::this_grid();

    int t = threadIdx.x;
    int lane = t & 63;
    int wid = __builtin_amdgcn_readfirstlane(t >> 6);   // wave id, 0..15
    int row0 = blockIdx.x * 128;               // 8 nodes x 16 batches

    // ---- y0 = inputs[:,0] @ w_in + b_in, straight into registers (both passes) ----
    float4 yr[2], accr[2];
#pragma unroll
    for (int p = 0; p < 2; p++) {
        int r = t >> 4, q = t & 15;            // pass-local row, float4-quad
        int tn = row0 + p * 64 + r;
        int n0 = tn >> 4, b0 = tn & 15;
        const float* ip = inputs + ((size_t)(b0 * NS) * NN + n0) * 2;
        float i0 = ip[0], i1 = ip[1];
        float4 wa = ((const float4*)w_in)[q];
        float4 wb = ((const float4*)(w_in + 64))[q];
        float4 bb = ((const float4*)b_in)[q];
        yr[p].x = i0 * wa.x + i1 * wb.x + bb.x;
        yr[p].y = i0 * wa.y + i1 * wb.y + bb.y;
        yr[p].z = i0 * wa.z + i1 * wb.z + bb.z;
        yr[p].w = i0 * wa.w + i1 * wb.w + bb.w;
        accr[p] = make_float4(0.f, 0.f, 0.f, 0.f);
    }

    for (int ev = 0; ev <= 48; ev++) {
        int mode = (ev == 0) ? 0 : ((ev - 1) & 3) + 1;   // 0,1,2,3,4,1,2,...
        bool last = (ev == 48);
        const uint2* htR; const float* estR; const float* edtR;
        uint2* htW; float* estW; float* edtW;
        if (ev & 1) { htR = htA; estR = estA; edtR = edtA; htW = htB; estW = estB; edtW = edtB; }
        else        { htR = htB; estR = estB; edtR = edtB; htW = htA; estW = estA; edtW = edtA; }

#pragma unroll
        for (int p = 0; p < 2; p++) {
            // ---------- phase 1: aggregation for this pass's 4 nodes ----------
            if (mode != 0) {
                int np = wid >> 2, bg = wid & 3;
                int n = blockIdx.x * 8 + p * 4 + np;
                int hd = lane >> 4;
                int o0 = offs[n], o1 = offs[n + 1];       // padded, multiple of 8
                int eoff = bg * 16 + (lane & 15);
                float edv = edtR[(size_t)n * 64 + eoff];
                const uint2* hbase = htR + (size_t)bg * 64 + lane;

                float d0 = 0.f, d1 = 0.f, d2 = 0.f, d3 = 0.f;
                float a0 = 0.f, a1 = 0.f, a2 = 0.f, a3 = 0.f;
                for (int base = o0; base < o1; base += 64) {
                    int cnt = o1 - base; if (cnt > 64) cnt = 64;
                    int svv = csr[base + (lane < cnt ? lane : cnt - 1)];
                    for (int j = 0; j < cnt; j += 4) {
                        int ss[4]; float es4[4]; uint2 hv4[4];
#pragma unroll
                        for (int qq = 0; qq < 4; qq++) ss[qq] = __builtin_amdgcn_readlane(svv, j + qq);
#pragma unroll
                        for (int qq = 0; qq < 4; qq++) es4[qq] = estR[(size_t)ss[qq] * 64 + eoff];
#pragma unroll
                        for (int qq = 0; qq < 4; qq++) hv4[qq] = hbase[(size_t)ss[qq] * 256];
#pragma unroll
                        for (int qq = 0; qq < 4; qq++) {
                            float e = es4[qq] + edv;
                            e = fmaxf(e, 0.2f * e);       // leaky_relu (slope<1, log2e-scaled)
                            float w = fexp2(e);           // sentinel -> exactly 0
                            float w0 = __shfl(w, hd);
                            float w1 = __shfl(w, 4 + hd);
                            float w2 = __shfl(w, 8 + hd);
                            float w3 = __shfl(w, 12 + hd);
                            float h0 = __uint_as_float(hv4[qq].x << 16);
                            float h1 = __uint_as_float(hv4[qq].x & 0xffff0000u);
                            float h2 = __uint_as_float(hv4[qq].y << 16);
                            float h3 = __uint_as_float(hv4[qq].y & 0xffff0000u);
                            d0 += w0; a0 += w0 * h0;
                            d1 += w1; a1 += w1 * h1;
                            d2 += w2; a2 += w2 * h2;
                            d3 += w3; a3 += w3 * h3;
                        }
                    }
                }
                float bgb = bias_g[lane];
                bool has = (o1 > o0);
                float r0 = has ? __builtin_amdgcn_rcpf(d0) : 0.f;
                float r1 = has ? __builtin_amdgcn_rcpf(d1) : 0.f;
                float r2 = has ? __builtin_amdgcn_rcpf(d2) : 0.f;
                float r3 = has ? __builtin_amdgcn_rcpf(d3) : 0.f;
                int rb = np * 16 + bg * 4;
                kvs[(rb + 0) * 64 + lane] = a0 * r0 + bgb;
                kvs[(rb + 1) * 64 + lane] = a1 * r1 + bgb;
                kvs[(rb + 2) * 64 + lane] = a2 * r2 + bgb;
                kvs[(rb + 3) * 64 + lane] = a3 * r3 + bgb;
                __syncthreads();
            }

            // ---------- phase 2: RK combine in registers ----------
            float4 z = yr[p];
            if (mode >= 1) {
                float4 kf = *(const float4*)&kvs[t * 4];  // row t>>4, quad t&15
                if (mode == 1) {
                    accr[p] = kf;
                    z.x += DT2C * kf.x; z.y += DT2C * kf.y; z.z += DT2C * kf.z; z.w += DT2C * kf.w;
                } else if (mode == 2) {
                    accr[p].x += 2.f * kf.x; accr[p].y += 2.f * kf.y;
                    accr[p].z += 2.f * kf.z; accr[p].w += 2.f * kf.w;
                    z.x += DT2C * kf.x; z.y += DT2C * kf.y; z.z += DT2C * kf.z; z.w += DT2C * kf.w;
                } else if (mode == 3) {
                    accr[p].x += 2.f * kf.x; accr[p].y += 2.f * kf.y;
                    accr[p].z += 2.f * kf.z; accr[p].w += 2.f * kf.w;
                    z.x += DTC * kf.x; z.y += DTC * kf.y; z.z += DTC * kf.z; z.w += DTC * kf.w;
                } else {                                  // mode 4
                    yr[p].x += DT6C * (accr[p].x + kf.x); yr[p].y += DT6C * (accr[p].y + kf.y);
                    yr[p].z += DT6C * (accr[p].z + kf.z); yr[p].w += DT6C * (accr[p].w + kf.w);
                    z = yr[p];
                }
            }
            if (last) {                       // final eval: y updated, no gemm
                __syncthreads();              // protect kvs reads from next pass's agg writes
                continue;
            }

            {
                int rr = t >> 4;
                int kkb = (t & 15) << 2;
                Zs[(kkb + 0) * 65 + rr] = z.x;
                Zs[(kkb + 1) * 65 + rr] = z.y;
                Zs[(kkb + 2) * 65 + rr] = z.z;
                Zs[(kkb + 3) * 65 + rr] = z.w;
            }
            __syncthreads();

            // ---------- phase 3: gemm, 4 cols/thread ----------
            const float* wcol = Wh + wid * 4;
            float a0 = 0.f, a1 = 0.f, a2 = 0.f, a3 = 0.f;
            for (int kk = 0; kk < 64; kk++) {
                float zk = Zs[kk * 65 + lane];
                float4 w = *(const float4*)(wcol + kk * 64);
                a0 += zk * w.x; a1 += zk * w.y; a2 += zk * w.z; a3 += zk * w.w;
            }

            // ---------- phase 4: epilogue ----------
            Hs[lane * 33 + wid * 2 + 0] = (unsigned int)f2bf(a0) | ((unsigned int)f2bf(a1) << 16);
            Hs[lane * 33 + wid * 2 + 1] = (unsigned int)f2bf(a2) | ((unsigned int)f2bf(a3) << 16);

            int head = wid >> 2, qp = wid & 3;
            const float* as = a_src + head * 16 + qp * 4;
            const float* ad = a_dst + head * 16 + qp * 4;
            Ps[wid][lane] = a0 * as[0] + a1 * as[1] + a2 * as[2] + a3 * as[3];
            Pd[wid][lane] = a0 * ad[0] + a1 * ad[1] + a2 * ad[2] + a3 * ad[3];
            __syncthreads();

            if (wid < 4) {                     // head = wid
                int tn2 = row0 + p * 64 + lane;
                float sv = (Ps[wid * 4 + 0][lane] + Ps[wid * 4 + 1][lane]
                          + Ps[wid * 4 + 2][lane] + Ps[wid * 4 + 3][lane]) * LOG2E;
                float dv = (Pd[wid * 4 + 0][lane] + Pd[wid * 4 + 1][lane]
                          + Pd[wid * 4 + 2][lane] + Pd[wid * 4 + 3][lane]) * LOG2E;
                estW[(size_t)tn2 * 4 + wid] = sv;
                edtW[(size_t)tn2 * 4 + wid] = dv;
            }

            if (t < 512) {                     // packed ht store (wave-uniform branch)
                int nbg = t >> 5;              // 0..15
                int np2 = nbg >> 2, bg2 = nbg & 3;
                int cp = t & 31;
                int rbase = np2 * 16 + bg2 * 4;
                unsigned int r0 = Hs[(rbase + 0) * 33 + cp];
                unsigned int r1 = Hs[(rbase + 1) * 33 + cp];
                unsigned int r2 = Hs[(rbase + 2) * 33 + cp];
                unsigned int r3 = Hs[(rbase + 3) * 33 + cp];
                uint4 o;
                o.x = (r0 & 0xffffu) | (r1 << 16);
                o.y = (r2 & 0xffffu) | (r3 << 16);
                o.z = (r0 >> 16) | (r1 & 0xffff0000u);
                o.w = (r2 >> 16) | (r3 & 0xffff0000u);
                int ng = blockIdx.x * 8 + p * 4 + np2;
                *(uint4*)((unsigned int*)htW + (((size_t)(ng * 4 + bg2)) * 64 + 2 * cp) * 2) = o;
            }
            __syncthreads();                   // pass isolation (Zs/Hs/kvs reuse)
        }

        if (last) break;
        grid.sync();                           // next eval's agg reads this eval's writes
    }

    // write final y for the MLP
#pragma unroll
    for (int p = 0; p < 2; p++) {
        float4* yo4 = (float4*)(yout + (size_t)(row0 + p * 64) * 64);
        yo4[t] = yr[p];
    }
}

// ---------------- final MLP: out = tanh(y@w1+b1)@w2+b2 ----------------
__global__ __launch_bounds__(256) void mlp_k(
    const float* __restrict__ yin,
    const float* __restrict__ w1, const float* __restrict__ b1,
    const float* __restrict__ w2, const float* __restrict__ b2,
    float* __restrict__ out)
{
    __shared__ float Zs[64 * 65];
    __shared__ float Ts[64 * 65];
    int t = threadIdx.x;
    int row0 = blockIdx.x * 64;
    const float4* y4 = (const float4*)(yin + (size_t)row0 * 64);
#pragma unroll
    for (int i = 0; i < 4; i++) {
        int flat = t + 256 * i;
        float4 z = y4[flat];
        int r = flat >> 4;
        int kkb = (flat & 15) << 2;
        Zs[(kkb + 0) * 65 + r] = z.x;
        Zs[(kkb + 1) * 65 + r] = z.y;
        Zs[(kkb + 2) * 65 + r] = z.z;
        Zs[(kkb + 3) * 65 + r] = z.w;
    }
    __syncthreads();

    int lane = t & 63;
    int g = __builtin_amdgcn_readfirstlane(t >> 6);
    float a[16];
#pragma unroll
    for (int j = 0; j < 16; j++) a[j] = 0.f;
    const float* w1g = w1 + g * 16;
    for (int kk = 0; kk < 64; kk++) {
        float zk = Zs[kk * 65 + lane];
        const float4* w4 = (const float4*)(w1g + kk * 64);
        float4 w0 = w4[0], w1v = w4[1], w2v = w4[2], w3v = w4[3];
        a[0] += zk * w0.x;  a[1] += zk * w0.y;  a[2] += zk * w0.z;  a[3] += zk * w0.w;
        a[4] += zk * w1v.x; a[5] += zk * w1v.y; a[6] += zk * w1v.z; a[7] += zk * w1v.w;
        a[8] += zk * w2v.x; a[9] += zk * w2v.y; a[10] += zk * w2v.z; a[11] += zk * w2v.w;
        a[12] += zk * w3v.x; a[13] += zk * w3v.y; a[14] += zk * w3v.z; a[15] += zk * w3v.w;
    }
    const float4* b1g = (const float4*)(b1 + g * 16);
    float4 bb0 = b1g[0], bb1 = b1g[1], bb2 = b1g[2], bb3 = b1g[3];
    float bb[16] = { bb0.x,bb0.y,bb0.z,bb0.w, bb1.x,bb1.y,bb1.z,bb1.w,
                     bb2.x,bb2.y,bb2.z,bb2.w, bb3.x,bb3.y,bb3.z,bb3.w };
#pragma unroll
    for (int j = 0; j < 16; j++) {
        float v = a[j] + bb[j];
        float ex = __expf(2.f * v);
        float tv = 1.f - 2.f / (ex + 1.f);
        Ts[(16 * g + j) * 65 + lane] = tv;
    }
    __syncthreads();

    float a2[16];
#pragma unroll
    for (int j = 0; j < 16; j++) a2[j] = 0.f;
    const float* w2g = w2 + g * 16;
    for (int kk = 0; kk < 64; kk++) {
        float tk = Ts[kk * 65 + lane];
        const float4* w4 = (const float4*)(w2g + kk * 64);
        float4 w0 = w4[0], w1v = w4[1], w2v = w4[2], w3v = w4[3];
        a2[0] += tk * w0.x;  a2[1] += tk * w0.y;  a2[2] += tk * w0.z;  a2[3] += tk * w0.w;
        a2[4] += tk * w1v.x; a2[5] += tk * w1v.y; a2[6] += tk * w1v.z; a2[7] += tk * w1v.w;
        a2[8] += tk * w2v.x; a2[9] += tk * w2v.y; a2[10] += tk * w2v.z; a2[11] += tk * w2v.w;
        a2[12] += tk * w3v.x; a2[13] += tk * w3v.y; a2[14] += tk * w3v.z; a2[15] += tk * w3v.w;
    }
    const float4* b2g = (const float4*)(b2 + g * 16);
    float4 c0 = b2g[0], c1 = b2g[1], c2 = b2g[2], c3 = b2g[3];
    int tn = row0 + lane;
    int n = tn >> 4, b = tn & 15;
    float4* o4 = (float4*)(out + ((size_t)b * NN + n) * 64 + g * 16);
    o4[0] = make_float4(a2[0] + c0.x, a2[1] + c0.y, a2[2] + c0.z, a2[3] + c0.w);
    o4[1] = make_float4(a2[4] + c1.x, a2[5] + c1.y, a2[6] + c1.z, a2[7] + c1.w);
    o4[2] = make_float4(a2[8] + c2.x, a2[9] + c2.y, a2[10] + c2.z, a2[11] + c2.w);
    o4[3] = make_float4(a2[12] + c3.x, a2[13] + c3.y, a2[14] + c3.z, a2[15] + c3.w);
}

extern "C" void kernel_launch(void* const* d_in, const int* in_sizes, int n_in,
                              void* d_out, int out_size, void* d_ws, size_t ws_size,
                              hipStream_t stream)
{
    const float* inputs = (const float*)d_in[0];
    const float* w_in   = (const float*)d_in[1];
    const float* b_in   = (const float*)d_in[2];
    const float* Wh     = (const float*)d_in[3];
    const float* bias_g = (const float*)d_in[4];
    const float* a_src  = (const float*)d_in[5];
    const float* a_dst  = (const float*)d_in[6];
    const float* w1     = (const float*)d_in[7];
    const float* b1     = (const float*)d_in[8];
    const float* w2     = (const float*)d_in[9];
    const float* b2     = (const float*)d_in[10];
    const int* src      = (const int*)d_in[11];
    const int* dst      = (const int*)d_in[12];
    float* out = (float*)d_out;

    float* ws = (float*)d_ws;
    const size_t SZ = (size_t)NROWS * 64;          // 2,097,152 floats (8 MB)
    const size_t HTU = 525312;                     // uint2 count incl. sentinel pad
    const size_t ESF = 131136;                     // est floats incl. sentinel row
    const size_t EDF = 131072;
    float* y   = ws;
    uint2* htA = (uint2*)(y + SZ);
    float* estA = (float*)(htA + HTU);
    float* edtA = estA + ESF;
    uint2* htB = (uint2*)(edtA + EDF);
    float* estB = (float*)(htB + HTU);
    float* edtB = estB + ESF;
    int* offs   = (int*)(edtB + EDF);              // 2049 used
    int* cursor = offs + 2064;
    int* deg    = cursor + 2048;
    int* csr    = deg + 2048;                      // CSRCAP ints

    prep_k<<<CSRCAP / 256, 256, 0, stream>>>(deg, csr, estA, estB);
    count_deg_k<<<NE / 256, 256, 0, stream>>>(dst, deg);
    scan_k<<<1, 1024, 0, stream>>>(deg, offs, cursor);
    scatter_k<<<NE / 256, 256, 0, stream>>>(src, dst, cursor, csr);

    void* args[] = {
        (void*)&inputs, (void*)&w_in, (void*)&b_in,
        (void*)&htA, (void*)&estA, (void*)&edtA,
        (void*)&htB, (void*)&estB, (void*)&edtB,
        (void*)&offs, (void*)&csr, (void*)&bias_g,
        (void*)&Wh, (void*)&a_src, (void*)&a_dst,
        (void*)&y
    };
    hipLaunchCooperativeKernel((void*)persist_k, dim3(256), dim3(1024), args, 0, stream);

    mlp_k<<<512, 256, 0, stream>>>(y, w1, b1, w2, b2, out);
}

// Round 9
// 1062.394 us; speedup vs baseline: 2.3182x; 2.3182x over previous
//
#include <hip/hip_runtime.h>
#include <hip/hip_cooperative_groups.h>

#define NB 16
#define NS 12
#define NN 2048
#define NE 32768
#define NROWS (NB*NN)          // 32768 rows of 64
#define DTC  0.1f
#define DT2C 0.05f
#define DT6C (0.1f/6.0f)
#define LOG2E 1.44269504088896f
#define CSRCAP 49152           // NE + pad(<=7*NN) rounded up

// Node-major state: row tn = n*16 + b.
// ht packed: uint2 at [(n*4+bg)*64 + c] = bf16 h for batches bg*4..bg*4+3, column c.
// est/edt: [n*64 + b*4 + head], pre-scaled by LOG2E.  est has a SENTINEL row at
// n=NN (-1e30 -> exp2 = 0) so CSR is padded to multiples of 8 edges.
// ht/est/edt double-buffered across evals.
//
// LDS is time-multiplexed through one 16.6KB buffer SH (kvs -> Zs -> Ps/Pd,
// separated by barriers) + 8.4KB Hs = 24.5KB/block, so TWO 1024-thread blocks
// co-reside per CU (32 waves) even under a 64KB runtime LDS view. This is what
// round 7 (49.7KB) was missing -> cooperative 512-block launch was rejected.
//
// Primary path: ONE cooperative kernel, 512 blocks, y/acc in registers,
// grid.sync() between evals. Fallback (occupancy gate or launch error):
// round-5-style 49 launches (proven 1053us).

__device__ __forceinline__ unsigned short f2bf(float f) {
    unsigned int u = __float_as_uint(f);
    u = u + 0x7fffu + ((u >> 16) & 1u);      // RTNE
    return (unsigned short)(u >> 16);
}
__device__ __forceinline__ float fexp2(float x) {
#if __has_builtin(__builtin_amdgcn_exp2f)
    return __builtin_amdgcn_exp2f(x);
#else
    return __expf(x * 0.69314718056f);
#endif
}

// ---------------- init (fallback only): y0 = inputs[:,0]@w_in + b_in ----------------
__global__ __launch_bounds__(256) void init_y_k(const float* __restrict__ inputs,
    const float* __restrict__ w_in, const float* __restrict__ b_in, float* __restrict__ y)
{
    int idx = blockIdx.x * 256 + threadIdx.x;     // < NROWS*64
    int hh = idx & 63;
    int tn = idx >> 6;
    int n = tn >> 4, b = tn & 15;
    const float* ip = inputs + ((size_t)(b * NS) * NN + n) * 2;
    y[idx] = ip[0] * w_in[hh] + ip[1] * w_in[64 + hh] + b_in[hh];
}

// ---------------- prep: zero deg, sentinel-fill csr, sentinel est rows ----------------
__global__ __launch_bounds__(256) void prep_k(int* __restrict__ deg, int* __restrict__ csr,
    float* __restrict__ estA, float* __restrict__ estB)
{
    int t = blockIdx.x * 256 + threadIdx.x;
    if (t < NN) deg[t] = 0;
    if (t < CSRCAP) csr[t] = NN;               // sentinel node
    if (t < 64) {
        estA[(size_t)NN * 64 + t] = -1e30f;    // exp2 -> 0
        estB[(size_t)NN * 64 + t] = -1e30f;
    }
}
__global__ __launch_bounds__(256) void count_deg_k(const int* __restrict__ dst, int* __restrict__ deg)
{
    int e = blockIdx.x * 256 + threadIdx.x;
    if (e < NE) atomicAdd(&deg[dst[e]], 1);
}
// prefix-sum of PADDED degrees (pad to multiple of 8)
__global__ __launch_bounds__(1024) void scan_k(const int* __restrict__ deg,
    int* __restrict__ offs, int* __restrict__ cursor)
{
    __shared__ int p[1024];
    int t = threadIdx.x;
    int d0 = (deg[2 * t] + 7) & ~7;
    int d1 = (deg[2 * t + 1] + 7) & ~7;
    p[t] = d0 + d1;
    __syncthreads();
    for (int d = 1; d < 1024; d <<= 1) {
        int v = (t >= d) ? p[t - d] : 0;
        __syncthreads();
        p[t] += v;
        __syncthreads();
    }
    int excl = (t > 0) ? p[t - 1] : 0;     // exclusive pair-sum
    offs[2 * t] = excl;       offs[2 * t + 1] = excl + d0;
    cursor[2 * t] = excl;     cursor[2 * t + 1] = excl + d0;
    if (t == 1023) offs[2048] = p[1023];
}
__global__ __launch_bounds__(256) void scatter_k(const int* __restrict__ src, const int* __restrict__ dst,
    int* __restrict__ cursor, int* __restrict__ csr)
{
    int e = blockIdx.x * 256 + threadIdx.x;
    if (e < NE) {
        int pos = atomicAdd(&cursor[dst[e]], 1);
        csr[pos] = src[e];
    }
}

// ---------------- shared device pieces ----------------
// agg for (node n, batch group bg): writes 4 k-rows into SH kvs region.
__device__ __forceinline__ void agg_into_sh(
    int n, int np, int bg, int lane,
    const uint2* __restrict__ htR, const float* __restrict__ estR, const float* __restrict__ edtR,
    const int* __restrict__ offs, const int* __restrict__ csr, const float* __restrict__ bias_g,
    float* SH)
{
    int hd = lane >> 4;
    int o0 = offs[n], o1 = offs[n + 1];        // padded, multiple of 8
    int eoff = bg * 16 + (lane & 15);
    float edv = edtR[(size_t)n * 64 + eoff];
    const uint2* hbase = htR + (size_t)bg * 64 + lane;

    float d0 = 0.f, d1 = 0.f, d2 = 0.f, d3 = 0.f;
    float a0 = 0.f, a1 = 0.f, a2 = 0.f, a3 = 0.f;
    for (int base = o0; base < o1; base += 64) {
        int cnt = o1 - base; if (cnt > 64) cnt = 64;
        int svv = csr[base + (lane < cnt ? lane : cnt - 1)];
        for (int j = 0; j < cnt; j += 4) {
            int ss[4]; float es4[4]; uint2 hv4[4];
#pragma unroll
            for (int qq = 0; qq < 4; qq++) ss[qq] = __builtin_amdgcn_readlane(svv, j + qq);
#pragma unroll
            for (int qq = 0; qq < 4; qq++) es4[qq] = estR[(size_t)ss[qq] * 64 + eoff];
#pragma unroll
            for (int qq = 0; qq < 4; qq++) hv4[qq] = hbase[(size_t)ss[qq] * 256];
#pragma unroll
            for (int qq = 0; qq < 4; qq++) {
                float e = es4[qq] + edv;
                e = fmaxf(e, 0.2f * e);        // leaky_relu (slope<1, log2e-scaled)
                float w = fexp2(e);            // sentinel -> exactly 0
                float w0 = __shfl(w, hd);
                float w1 = __shfl(w, 4 + hd);
                float w2 = __shfl(w, 8 + hd);
                float w3 = __shfl(w, 12 + hd);
                float h0 = __uint_as_float(hv4[qq].x << 16);
                float h1 = __uint_as_float(hv4[qq].x & 0xffff0000u);
                float h2 = __uint_as_float(hv4[qq].y << 16);
                float h3 = __uint_as_float(hv4[qq].y & 0xffff0000u);
                d0 += w0; a0 += w0 * h0;
                d1 += w1; a1 += w1 * h1;
                d2 += w2; a2 += w2 * h2;
                d3 += w3; a3 += w3 * h3;
            }
        }
    }
    float bgb = bias_g[lane];
    bool has = (o1 > o0);
    float r0 = has ? __builtin_amdgcn_rcpf(d0) : 0.f;
    float r1 = has ? __builtin_amdgcn_rcpf(d1) : 0.f;
    float r2 = has ? __builtin_amdgcn_rcpf(d2) : 0.f;
    float r3 = has ? __builtin_amdgcn_rcpf(d3) : 0.f;
    int rb = np * 16 + bg * 4;
    SH[(rb + 0) * 64 + lane] = a0 * r0 + bgb;
    SH[(rb + 1) * 64 + lane] = a1 * r1 + bgb;
    SH[(rb + 2) * 64 + lane] = a2 * r2 + bgb;
    SH[(rb + 3) * 64 + lane] = a3 * r3 + bgb;
}

// gemm (h = z@Wh) + epilogue (ht/est/edt stores). SH must be free on entry
// (barriered); leaves SH/Hs "in use" until next block-wide barrier.
__device__ __forceinline__ void gemm_epi(
    int row0, int nodeBase, int t, int lane, int wid, float4 z,
    const float* __restrict__ Wh, const float* __restrict__ a_src, const float* __restrict__ a_dst,
    uint2* __restrict__ htW, float* __restrict__ estW, float* __restrict__ edtW,
    float* SH, unsigned int* Hs)
{
    {   // stage z transposed: Zs[k][r] at SH[k*65+r]
        int rr = t >> 4;
        int kkb = (t & 15) << 2;
        SH[(kkb + 0) * 65 + rr] = z.x;
        SH[(kkb + 1) * 65 + rr] = z.y;
        SH[(kkb + 2) * 65 + rr] = z.z;
        SH[(kkb + 3) * 65 + rr] = z.w;
    }
    __syncthreads();

    const float* wcol = Wh + wid * 4;          // wave-uniform -> scalar loads
    float a0 = 0.f, a1 = 0.f, a2 = 0.f, a3 = 0.f;
    for (int kk = 0; kk < 64; kk++) {
        float zk = SH[kk * 65 + lane];
        float4 w = *(const float4*)(wcol + kk * 64);
        a0 += zk * w.x; a1 += zk * w.y; a2 += zk * w.z; a3 += zk * w.w;
    }
    __syncthreads();                           // all Zs reads done; SH reusable

    Hs[lane * 33 + wid * 2 + 0] = (unsigned int)f2bf(a0) | ((unsigned int)f2bf(a1) << 16);
    Hs[lane * 33 + wid * 2 + 1] = (unsigned int)f2bf(a2) | ((unsigned int)f2bf(a3) << 16);

    int head = wid >> 2, qp = wid & 3;
    const float* as = a_src + head * 16 + qp * 4;
    const float* ad = a_dst + head * 16 + qp * 4;
    SH[wid * 64 + lane]        = a0 * as[0] + a1 * as[1] + a2 * as[2] + a3 * as[3];
    SH[1024 + wid * 64 + lane] = a0 * ad[0] + a1 * ad[1] + a2 * ad[2] + a3 * ad[3];
    __syncthreads();

    if (wid < 4) {                             // head = wid
        int tn2 = row0 + lane;
        float sv = (SH[(wid * 4 + 0) * 64 + lane] + SH[(wid * 4 + 1) * 64 + lane]
                  + SH[(wid * 4 + 2) * 64 + lane] + SH[(wid * 4 + 3) * 64 + lane]) * LOG2E;
        float dv = (SH[1024 + (wid * 4 + 0) * 64 + lane] + SH[1024 + (wid * 4 + 1) * 64 + lane]
                  + SH[1024 + (wid * 4 + 2) * 64 + lane] + SH[1024 + (wid * 4 + 3) * 64 + lane]) * LOG2E;
        estW[(size_t)tn2 * 4 + wid] = sv;      // == [n*64 + b*4 + head]
        edtW[(size_t)tn2 * 4 + wid] = dv;
    }
    if (t < 512) {                             // packed ht store (wave-uniform branch)
        int nbg = t >> 5;                      // 0..15
        int np2 = nbg >> 2, bg2 = nbg & 3;
        int cp = t & 31;
        int rbase = np2 * 16 + bg2 * 4;
        unsigned int r0 = Hs[(rbase + 0) * 33 + cp];
        unsigned int r1 = Hs[(rbase + 1) * 33 + cp];
        unsigned int r2 = Hs[(rbase + 2) * 33 + cp];
        unsigned int r3 = Hs[(rbase + 3) * 33 + cp];
        uint4 o;
        o.x = (r0 & 0xffffu) | (r1 << 16);
        o.y = (r2 & 0xffffu) | (r3 << 16);
        o.z = (r0 >> 16) | (r1 & 0xffff0000u);
        o.w = (r2 >> 16) | (r3 & 0xffff0000u);
        int ng = nodeBase + np2;
        *(uint4*)((unsigned int*)htW + (((size_t)(ng * 4 + bg2)) * 64 + 2 * cp) * 2) = o;
    }
}

// ---------------- PRIMARY: cooperative persistent kernel, 512 blocks ----------------
__global__ __launch_bounds__(1024, 4) void coop_k(
    const float* __restrict__ inputs, const float* __restrict__ w_in, const float* __restrict__ b_in,
    uint2* __restrict__ htA, float* __restrict__ estA, float* __restrict__ edtA,
    uint2* __restrict__ htB, float* __restrict__ estB, float* __restrict__ edtB,
    const int* __restrict__ offs, const int* __restrict__ csr, const float* __restrict__ bias_g,
    const float* __restrict__ Wh, const float* __restrict__ a_src, const float* __restrict__ a_dst,
    float* __restrict__ yout)
{
    __shared__ float SH[4160];                 // kvs / Zs / Ps,Pd (time-multiplexed)
    __shared__ unsigned int Hs[64 * 33];
    cooperative_groups::grid_group grid = cooperative_groups::this_grid();

    int t = threadIdx.x;
    int lane = t & 63;
    int wid = __builtin_amdgcn_readfirstlane(t >> 6);
    int row0 = blockIdx.x * 64;                // 4 nodes x 16 batches

    // y0 into registers
    float4 yr, accr;
    {
        int r = t >> 4, q = t & 15;
        int tn = row0 + r;
        int n0 = tn >> 4, b0 = tn & 15;
        const float* ip = inputs + ((size_t)(b0 * NS) * NN + n0) * 2;
        float i0 = ip[0], i1 = ip[1];
        float4 wa = ((const float4*)w_in)[q];
        float4 wb = ((const float4*)(w_in + 64))[q];
        float4 bb = ((const float4*)b_in)[q];
        yr.x = i0 * wa.x + i1 * wb.x + bb.x;
        yr.y = i0 * wa.y + i1 * wb.y + bb.y;
        yr.z = i0 * wa.z + i1 * wb.z + bb.z;
        yr.w = i0 * wa.w + i1 * wb.w + bb.w;
        accr = make_float4(0.f, 0.f, 0.f, 0.f);
    }

    for (int ev = 0; ev <= 48; ev++) {
        int mode = (ev == 0) ? 0 : ((ev - 1) & 3) + 1;   // 0,1,2,3,4,1,2,...
        bool last = (ev == 48);
        const uint2* htR; const float* estR; const float* edtR;
        uint2* htW; float* estW; float* edtW;
        if (ev & 1) { htR = htA; estR = estA; edtR = edtA; htW = htB; estW = estB; edtW = edtB; }
        else        { htR = htB; estR = estB; edtR = edtB; htW = htA; estW = estA; edtW = edtA; }

        float4 z;
        if (mode != 0) {
            int np = wid >> 2, bg = wid & 3;
            agg_into_sh(blockIdx.x * 4 + np, np, bg, lane, htR, estR, edtR, offs, csr, bias_g, SH);
            __syncthreads();
            float4 kf = *(const float4*)&SH[t * 4];
            z = yr;
            if (mode == 1) {
                accr = kf;
                z.x += DT2C * kf.x; z.y += DT2C * kf.y; z.z += DT2C * kf.z; z.w += DT2C * kf.w;
            } else if (mode == 2) {
                accr.x += 2.f * kf.x; accr.y += 2.f * kf.y; accr.z += 2.f * kf.z; accr.w += 2.f * kf.w;
                z.x += DT2C * kf.x; z.y += DT2C * kf.y; z.z += DT2C * kf.z; z.w += DT2C * kf.w;
            } else if (mode == 3) {
                accr.x += 2.f * kf.x; accr.y += 2.f * kf.y; accr.z += 2.f * kf.z; accr.w += 2.f * kf.w;
                z.x += DTC * kf.x; z.y += DTC * kf.y; z.z += DTC * kf.z; z.w += DTC * kf.w;
            } else {                                      // mode 4
                yr.x += DT6C * (accr.x + kf.x); yr.y += DT6C * (accr.y + kf.y);
                yr.z += DT6C * (accr.z + kf.z); yr.w += DT6C * (accr.w + kf.w);
                z = yr;
            }
            if (last) break;
            __syncthreads();                   // kf reads done; SH free for Zs
        } else {
            z = yr;
        }

        gemm_epi(row0, blockIdx.x * 4, t, lane, wid, z,
                 Wh, a_src, a_dst, htW, estW, edtW, SH, Hs);
        grid.sync();                           // order stores vs next eval's agg reads
    }

    float4* yo4 = (float4*)(yout + (size_t)row0 * 64);
    yo4[t] = yr;
}

// ---------------- FALLBACK: single-eval fused kernel (round-5 structure) ----------------
// mode 0: z=y | 1: k1 | 2: k2 | 3: k3 | 4: k4+y-update+gemm | 5: k4+y-update, stop
__global__ __launch_bounds__(1024, 4) void fused1_k(
    const float* yin, float* __restrict__ acc, float* yout,
    const uint2* __restrict__ htR, const float* __restrict__ estR, const float* __restrict__ edtR,
    uint2* __restrict__ htW, float* __restrict__ estW, float* __restrict__ edtW,
    const int* __restrict__ offs, const int* __restrict__ csr, const float* __restrict__ bias_g,
    const float* __restrict__ Wh, const float* __restrict__ a_src, const float* __restrict__ a_dst,
    int mode)
{
    __shared__ float SH[4160];
    __shared__ unsigned int Hs[64 * 33];
    int t = threadIdx.x;
    int lane = t & 63;
    int wid = __builtin_amdgcn_readfirstlane(t >> 6);
    int row0 = blockIdx.x * 64;

    float4 z;
    if (mode != 0) {
        int np = wid >> 2, bg = wid & 3;
        agg_into_sh(blockIdx.x * 4 + np, np, bg, lane, htR, estR, edtR, offs, csr, bias_g, SH);
        __syncthreads();
        float4 kf = *(const float4*)&SH[t * 4];
        float4 yv = ((const float4*)(yin + (size_t)row0 * 64))[t];
        float4* a4g = (float4*)(acc + (size_t)row0 * 64);
        if (mode == 1) {
            a4g[t] = kf;
            z = yv;
            z.x += DT2C * kf.x; z.y += DT2C * kf.y; z.z += DT2C * kf.z; z.w += DT2C * kf.w;
        } else if (mode == 2) {
            float4 av = a4g[t];
            av.x += 2.f * kf.x; av.y += 2.f * kf.y; av.z += 2.f * kf.z; av.w += 2.f * kf.w;
            a4g[t] = av;
            z = yv;
            z.x += DT2C * kf.x; z.y += DT2C * kf.y; z.z += DT2C * kf.z; z.w += DT2C * kf.w;
        } else if (mode == 3) {
            float4 av = a4g[t];
            av.x += 2.f * kf.x; av.y += 2.f * kf.y; av.z += 2.f * kf.z; av.w += 2.f * kf.w;
            a4g[t] = av;
            z = yv;
            z.x += DTC * kf.x; z.y += DTC * kf.y; z.z += DTC * kf.z; z.w += DTC * kf.w;
        } else {                               // 4 or 5
            float4 av = a4g[t];
            yv.x += DT6C * (av.x + kf.x); yv.y += DT6C * (av.y + kf.y);
            yv.z += DT6C * (av.z + kf.z); yv.w += DT6C * (av.w + kf.w);
            ((float4*)(yout + (size_t)row0 * 64))[t] = yv;
            z = yv;
        }
        if (mode == 5) return;
        __syncthreads();                       // kf reads done; SH free for Zs
    } else {
        z = ((const float4*)(yin + (size_t)row0 * 64))[t];
    }
    gemm_epi(row0, blockIdx.x * 4, t, lane, wid, z,
             Wh, a_src, a_dst, htW, estW, edtW, SH, Hs);
}

// ---------------- final MLP: out = tanh(y@w1+b1)@w2+b2 ----------------
__global__ __launch_bounds__(256) void mlp_k(
    const float* __restrict__ yin,
    const float* __restrict__ w1, const float* __restrict__ b1,
    const float* __restrict__ w2, const float* __restrict__ b2,
    float* __restrict__ out)
{
    __shared__ float Zs[64 * 65];
    __shared__ float Ts[64 * 65];
    int t = threadIdx.x;
    int row0 = blockIdx.x * 64;
    const float4* y4 = (const float4*)(yin + (size_t)row0 * 64);
#pragma unroll
    for (int i = 0; i < 4; i++) {
        int flat = t + 256 * i;
        float4 z = y4[flat];
        int r = flat >> 4;
        int kkb = (flat & 15) << 2;
        Zs[(kkb + 0) * 65 + r] = z.x;
        Zs[(kkb + 1) * 65 + r] = z.y;
        Zs[(kkb + 2) * 65 + r] = z.z;
        Zs[(kkb + 3) * 65 + r] = z.w;
    }
    __syncthreads();

    int lane = t & 63;
    int g = __builtin_amdgcn_readfirstlane(t >> 6);
    float a[16];
#pragma unroll
    for (int j = 0; j < 16; j++) a[j] = 0.f;
    const float* w1g = w1 + g * 16;
    for (int kk = 0; kk < 64; kk++) {
        float zk = Zs[kk * 65 + lane];
        const float4* w4 = (const float4*)(w1g + kk * 64);
        float4 w0 = w4[0], w1v = w4[1], w2v = w4[2], w3v = w4[3];
        a[0] += zk * w0.x;  a[1] += zk * w0.y;  a[2] += zk * w0.z;  a[3] += zk * w0.w;
        a[4] += zk * w1v.x; a[5] += zk * w1v.y; a[6] += zk * w1v.z; a[7] += zk * w1v.w;
        a[8] += zk * w2v.x; a[9] += zk * w2v.y; a[10] += zk * w2v.z; a[11] += zk * w2v.w;
        a[12] += zk * w3v.x; a[13] += zk * w3v.y; a[14] += zk * w3v.z; a[15] += zk * w3v.w;
    }
    const float4* b1g = (const float4*)(b1 + g * 16);
    float4 bb0 = b1g[0], bb1 = b1g[1], bb2 = b1g[2], bb3 = b1g[3];
    float bb[16] = { bb0.x,bb0.y,bb0.z,bb0.w, bb1.x,bb1.y,bb1.z,bb1.w,
                     bb2.x,bb2.y,bb2.z,bb2.w, bb3.x,bb3.y,bb3.z,bb3.w };
#pragma unroll
    for (int j = 0; j < 16; j++) {
        float v = a[j] + bb[j];
        float ex = __expf(2.f * v);
        float tv = 1.f - 2.f / (ex + 1.f);
        Ts[(16 * g + j) * 65 + lane] = tv;
    }
    __syncthreads();

    float a2[16];
#pragma unroll
    for (int j = 0; j < 16; j++) a2[j] = 0.f;
    const float* w2g = w2 + g * 16;
    for (int kk = 0; kk < 64; kk++) {
        float tk = Ts[kk * 65 + lane];
        const float4* w4 = (const float4*)(w2g + kk * 64);
        float4 w0 = w4[0], w1v = w4[1], w2v = w4[2], w3v = w4[3];
        a2[0] += tk * w0.x;  a2[1] += tk * w0.y;  a2[2] += tk * w0.z;  a2[3] += tk * w0.w;
        a2[4] += tk * w1v.x; a2[5] += tk * w1v.y; a2[6] += tk * w1v.z; a2[7] += tk * w1v.w;
        a2[8] += tk * w2v.x; a2[9] += tk * w2v.y; a2[10] += tk * w2v.z; a2[11] += tk * w2v.w;
        a2[12] += tk * w3v.x; a2[13] += tk * w3v.y; a2[14] += tk * w3v.z; a2[15] += tk * w3v.w;
    }
    const float4* b2g = (const float4*)(b2 + g * 16);
    float4 c0 = b2g[0], c1 = b2g[1], c2 = b2g[2], c3 = b2g[3];
    int tn = row0 + lane;
    int n = tn >> 4, b = tn & 15;
    float4* o4 = (float4*)(out + ((size_t)b * NN + n) * 64 + g * 16);
    o4[0] = make_float4(a2[0] + c0.x, a2[1] + c0.y, a2[2] + c0.z, a2[3] + c0.w);
    o4[1] = make_float4(a2[4] + c1.x, a2[5] + c1.y, a2[6] + c1.z, a2[7] + c1.w);
    o4[2] = make_float4(a2[8] + c2.x, a2[9] + c2.y, a2[10] + c2.z, a2[11] + c2.w);
    o4[3] = make_float4(a2[12] + c3.x, a2[13] + c3.y, a2[14] + c3.z, a2[15] + c3.w);
}

extern "C" void kernel_launch(void* const* d_in, const int* in_sizes, int n_in,
                              void* d_out, int out_size, void* d_ws, size_t ws_size,
                              hipStream_t stream)
{
    const float* inputs = (const float*)d_in[0];
    const float* w_in   = (const float*)d_in[1];
    const float* b_in   = (const float*)d_in[2];
    const float* Wh     = (const float*)d_in[3];
    const float* bias_g = (const float*)d_in[4];
    const float* a_src  = (const float*)d_in[5];
    const float* a_dst  = (const float*)d_in[6];
    const float* w1     = (const float*)d_in[7];
    const float* b1     = (const float*)d_in[8];
    const float* w2     = (const float*)d_in[9];
    const float* b2     = (const float*)d_in[10];
    const int* src      = (const int*)d_in[11];
    const int* dst      = (const int*)d_in[12];
    float* out = (float*)d_out;

    float* ws = (float*)d_ws;
    const size_t SZ = (size_t)NROWS * 64;          // 2,097,152 floats (8 MB)
    const size_t HTU = 525312;                     // uint2 count incl. sentinel pad
    const size_t ESF = 131136;                     // est floats incl. sentinel row
    const size_t EDF = 131072;
    float* y    = ws;
    float* acc  = y + SZ;                          // fallback only
    uint2* htA  = (uint2*)(acc + SZ);
    float* estA = (float*)(htA + HTU);
    float* edtA = estA + ESF;
    uint2* htB  = (uint2*)(edtA + EDF);
    float* estB = (float*)(htB + HTU);
    float* edtB = estB + ESF;
    int* offs   = (int*)(edtB + EDF);              // 2049 used
    int* cursor = offs + 2064;
    int* deg    = cursor + 2048;
    int* csr    = deg + 2048;                      // CSRCAP ints

    prep_k<<<CSRCAP / 256, 256, 0, stream>>>(deg, csr, estA, estB);
    count_deg_k<<<NE / 256, 256, 0, stream>>>(dst, deg);
    scan_k<<<1, 1024, 0, stream>>>(deg, offs, cursor);
    scatter_k<<<NE / 256, 256, 0, stream>>>(src, dst, cursor, csr);

    // occupancy gate: need 2 blocks/CU for a 512-block cooperative launch
    int nb = 0;
    hipError_t qerr = hipOccupancyMaxActiveBlocksPerMultiprocessor(
        &nb, reinterpret_cast<const void*>(coop_k), 1024, 0);
    bool coop_done = false;
    if (qerr == hipSuccess && nb >= 2) {
        void* args[] = {
            (void*)&inputs, (void*)&w_in, (void*)&b_in,
            (void*)&htA, (void*)&estA, (void*)&edtA,
            (void*)&htB, (void*)&estB, (void*)&edtB,
            (void*)&offs, (void*)&csr, (void*)&bias_g,
            (void*)&Wh, (void*)&a_src, (void*)&a_dst,
            (void*)&y
        };
        hipError_t lerr = hipLaunchCooperativeKernel((void*)coop_k, dim3(512), dim3(1024),
                                                     args, 0, stream);
        coop_done = (lerr == hipSuccess);
    }

    if (!coop_done) {
        // fallback: proven multi-launch path (round-5 structure)
        init_y_k<<<NROWS * 64 / 256, 256, 0, stream>>>(inputs, w_in, b_in, y);
        const uint2* htR = htB; const float* estR = estB; const float* edtR = edtB;
        uint2* htW = htA; float* estW = estA; float* edtW = edtA;
        fused1_k<<<512, 1024, 0, stream>>>(y, acc, y, htR, estR, edtR, htW, estW, edtW,
                                           offs, csr, bias_g, Wh, a_src, a_dst, 0);
        // after eval0, reader buffer = A
        const uint2* hR = htA; const float* eR = estA; const float* dR = edtA;
        uint2* hW = htB; float* eW = estB; float* dW = edtB;
        for (int step = 0; step < 12; step++) {
            for (int st = 1; st <= 4; st++) {
                int mode = (step == 11 && st == 4) ? 5 : st;
                fused1_k<<<512, 1024, 0, stream>>>(y, acc, y, hR, eR, dR, hW, eW, dW,
                                                   offs, csr, bias_g, Wh, a_src, a_dst, mode);
                const uint2* th = hR; hR = hW; hW = (uint2*)th;
                const float* te = eR; eR = eW; eW = (float*)te;
                const float* td = dR; dR = dW; dW = (float*)td;
            }
        }
    }

    mlp_k<<<512, 256, 0, stream>>>(y, w1, b1, w2, b2, out);
}